// Round 4
// baseline (75.462 us; speedup 1.0000x reference)
//
#include <hip/hip_runtime.h>

// SIMcLoss: x [8192, 256] fp32 -> scalar.
// loss = (||Xn^T Xn||_F^2 - n) / (n^2 - n), computed on the 256x256 Gram
// matrix. bf16 (RNE) MFMA, symmetric 64x64 tiles (10 upper pairs, off-diag
// weight 2), split-K over 512-row chunks, atomicAdd into G, last-block
// ticket does the weighted square-reduce in-kernel. 2 dispatches total.
#define D 256
#define TILE 64
#define NPAIRS 10
#define CHUNK 512
#define EPS 1e-8f

typedef __attribute__((ext_vector_type(8))) short bf16x8;
typedef __attribute__((ext_vector_type(4))) float f32x4;

__device__ __forceinline__ void pair_decode(int p, int& ta, int& tb) {
  if (p < 4)      { ta = 0; tb = p; }
  else if (p < 7) { ta = 1; tb = p - 3; }
  else if (p < 9) { ta = 2; tb = p - 5; }
  else            { ta = 3; tb = 3; }
}

// swizzled short-index into Xt[col][64 rows] (row-stride 64 shorts = 128 B).
// XOR bits 3..5 of row with g(col): b128 frag reads ~2-way, b64 writes 4-way.
__device__ __forceinline__ int swz(int col, int r) {
  int g = ((col >> 2) & 7) ^ ((col & 3) << 1);
  return col * 64 + (r ^ (g << 3));
}

// round-to-nearest-even fp32 -> bf16 (truncation would bias S by ~-2e3)
__device__ __forceinline__ unsigned short rne_bf16(float f) {
  unsigned u = __float_as_uint(f);
  return (unsigned short)((u + 0x7fffu + ((u >> 16) & 1u)) >> 16);
}

// ---------------------------------------------------------------------------
// Kernel 1: row inverse norms (one wave per row) + zero G (256 KB) + cnt.
// ---------------------------------------------------------------------------
__global__ __launch_bounds__(256) void k_prep(
    const float* __restrict__ x, float* __restrict__ inv,
    unsigned int* __restrict__ cnt, float* __restrict__ G, int N) {
  if (blockIdx.x == 0 && threadIdx.x == 0) *cnt = 0u;
  if (blockIdx.x < 64) {
    reinterpret_cast<float4*>(G)[blockIdx.x * 256 + threadIdx.x] =
        make_float4(0.f, 0.f, 0.f, 0.f);
  }
  int wave = (blockIdx.x * blockDim.x + threadIdx.x) >> 6;
  int lane = threadIdx.x & 63;
  if (wave >= N) return;
  const float4 v = reinterpret_cast<const float4*>(x + (size_t)wave * D)[lane];
  float s = v.x * v.x + v.y * v.y + v.z * v.z + v.w * v.w;
  #pragma unroll
  for (int o = 32; o > 0; o >>= 1) s += __shfl_xor(s, o);
  if (lane == 0) inv[wave] = 1.0f / fmaxf(sqrtf(s), EPS);
}

// ---------------------------------------------------------------------------
// Kernel 2: fused Gram + reduce. grid (NPAIRS, N/CHUNK), 512 threads.
// Per block: 8 sub-chunks of 64 rows {reg-prefetch -> LDS transpose (bf16,
// swizzled) -> 2 barriers -> MFMA}, atomicAdd 64x64 into G, ticket; last
// block reduces G with agent-scope loads and writes the loss.
// ---------------------------------------------------------------------------
__global__ __launch_bounds__(512) void k_fused(
    const float* __restrict__ x, const float* __restrict__ inv,
    float* __restrict__ G, unsigned int* __restrict__ cnt,
    float* __restrict__ out, int N, int nblocks) {
  int ta, tb; pair_decode(blockIdx.x, ta, tb);
  const bool same = (ta == tb);
  const int row0 = blockIdx.y * CHUNK;

  __shared__ short X[128 * 64];     // [col][row], cols 0..63=A, 64..127=B
  const int tid = threadIdx.x;

  // staging task: 4 rows x 4 cols micro-transpose
  const int lcb = same ? 4 : 5;                 // log2(col-blocks)
  const int ntask = 16 << lcb;                  // 256 or 512
  const bool active = tid < ntask;
  const int c0 = (tid & ((1 << lcb) - 1)) << 2; // LDS col base
  const int r0 = (active ? (tid >> lcb) : 0) << 2;
  const int gc0 = (c0 < TILE) ? ta * TILE + c0 : tb * TILE + (c0 - TILE);

  // MFMA decomposition: wave w owns 16x32 of the 64x64 tile
  const int w = tid >> 6, lane = tid & 63;
  const int i0 = (w >> 1) << 4;                 // 0,16,32,48
  const int j0 = (w & 1) << 5;                  // 0,32
  const int lm = lane & 15, lk = lane >> 4;
  const int bbase = same ? 0 : 64;

  f32x4 zero = {0.f, 0.f, 0.f, 0.f};
  f32x4 acc[2] = {zero, zero};

  float4 pv[4]; float4 piv;
  if (active) {
    piv = *reinterpret_cast<const float4*>(&inv[row0 + r0]);
    const float* xb = x + (size_t)(row0 + r0) * D + gc0;
    #pragma unroll
    for (int jj = 0; jj < 4; ++jj)
      pv[jj] = *reinterpret_cast<const float4*>(xb + (size_t)jj * D);
  }

  const int NSUB = CHUNK / 64;                  // 8
  for (int s = 0; s < NSUB; ++s) {
    if (active) {
      const float ivv[4] = {piv.x, piv.y, piv.z, piv.w};
      unsigned short hh[4][4];
      #pragma unroll
      for (int jj = 0; jj < 4; ++jj) {
        const float vv[4] = {pv[jj].x, pv[jj].y, pv[jj].z, pv[jj].w};
        #pragma unroll
        for (int cc = 0; cc < 4; ++cc)
          hh[jj][cc] = rne_bf16(vv[cc] * ivv[jj]);
      }
      #pragma unroll
      for (int cc = 0; cc < 4; ++cc)
        *reinterpret_cast<ushort4*>(&X[swz(c0 + cc, r0)]) =
            make_ushort4(hh[0][cc], hh[1][cc], hh[2][cc], hh[3][cc]);
      if (s + 1 < NSUB) {                       // prefetch next sub-chunk
        const int nr0 = row0 + (s + 1) * 64 + r0;
        piv = *reinterpret_cast<const float4*>(&inv[nr0]);
        const float* xb = x + (size_t)nr0 * D + gc0;
        #pragma unroll
        for (int jj = 0; jj < 4; ++jj)
          pv[jj] = *reinterpret_cast<const float4*>(xb + (size_t)jj * D);
      }
    }
    __syncthreads();
    #pragma unroll
    for (int rr = 0; rr < 64; rr += 32) {
      const int rbase = rr + lk * 8;
      bf16x8 A  = *reinterpret_cast<const bf16x8*>(&X[swz(i0 + lm, rbase)]);
      bf16x8 B0 = *reinterpret_cast<const bf16x8*>(&X[swz(bbase + j0 + lm, rbase)]);
      bf16x8 B1 = *reinterpret_cast<const bf16x8*>(&X[swz(bbase + j0 + 16 + lm, rbase)]);
      acc[0] = __builtin_amdgcn_mfma_f32_16x16x32_bf16(A, B0, acc[0], 0, 0, 0);
      acc[1] = __builtin_amdgcn_mfma_f32_16x16x32_bf16(A, B1, acc[1], 0, 0, 0);
    }
    __syncthreads();
  }

  // C/D layout (m89): col = lane&15, row = (lane>>4)*4 + reg
  const int grow0 = ta * TILE + i0 + lk * 4;
  const int gcol0 = tb * TILE + j0 + lm;
  #pragma unroll
  for (int jt = 0; jt < 2; ++jt)
    #pragma unroll
    for (int rg = 0; rg < 4; ++rg)
      atomicAdd(&G[(grow0 + rg) * D + gcol0 + jt * 16], acc[jt][rg]);

  __threadfence();
  __syncthreads();
  __shared__ int islast;
  if (tid == 0) {
    unsigned int old = __hip_atomic_fetch_add(cnt, 1u, __ATOMIC_ACQ_REL,
                                              __HIP_MEMORY_SCOPE_AGENT);
    islast = (old == (unsigned int)(nblocks - 1));
  }
  __syncthreads();
  if (!islast) return;

  // last block: weighted square-sum of G (agent-scope loads for coherence)
  __threadfence();
  float s = 0.f;
  for (int idx = tid; idx < D * D; idx += 512) {
    int i = idx >> 8, j = idx & 255;
    int A_ = i >> 6, B_ = j >> 6;
    if (A_ > B_) continue;                      // lower tiles are zero
    float v = __hip_atomic_load(&G[idx], __ATOMIC_RELAXED,
                                __HIP_MEMORY_SCOPE_AGENT);
    float wt = (A_ == B_) ? 1.f : 2.f;
    s += wt * v * v;
  }
  #pragma unroll
  for (int o = 32; o > 0; o >>= 1) s += __shfl_xor(s, o);
  __shared__ float red[8];
  if (lane == 0) red[w] = s;
  __syncthreads();
  if (tid == 0) {
    float S = 0.f;
    #pragma unroll
    for (int q = 0; q < 8; ++q) S += red[q];
    float nf = (float)N;
    out[0] = (S - nf) / (nf * nf - nf);
  }
}

extern "C" void kernel_launch(void* const* d_in, const int* in_sizes, int n_in,
                              void* d_out, int out_size, void* d_ws, size_t ws_size,
                              hipStream_t stream) {
  const float* x = (const float*)d_in[0];
  float* out = (float*)d_out;
  const int N = in_sizes[0] / D;       // 8192
  const int nchunk = N / CHUNK;        // 16
  const int nblocks = NPAIRS * nchunk; // 160

  // ws layout (floats): inv[N] | cnt | pad to +64 | G[256*256]
  float* inv = (float*)d_ws;
  unsigned int* cnt = (unsigned int*)(inv + N);
  float* G = inv + N + 64;

  k_prep<<<dim3(N / 4), dim3(256), 0, stream>>>(x, inv, cnt, G, N);
  k_fused<<<dim3(NPAIRS, nchunk), dim3(512), 0, stream>>>(
      x, inv, G, cnt, out, N, nblocks);
}

// Round 5
// 25.812 us; speedup vs baseline: 2.9235x; 2.9235x over previous
//
#include <hip/hip_runtime.h>

// SIMcLoss: x [8192, 256] fp32 -> scalar.
// loss = (||Xn^T Xn||_F^2 - n)/(n^2 - n) on the 256x256 Gram matrix.
// bf16 (RNE) MFMA, symmetric 64x64 tiles (10 upper pairs, off-diag weight 2),
// split-K over 512-row chunks -> per-block slab partials (NO atomics),
// 160-block coalesced reduce with last-block ticket. 3 dispatches.
#define D 256
#define TILE 64
#define NPAIRS 10
#define CHUNK 512
#define EPS 1e-8f

typedef __attribute__((ext_vector_type(8))) short bf16x8;
typedef __attribute__((ext_vector_type(4))) float f32x4;

__device__ __forceinline__ void pair_decode(int p, int& ta, int& tb) {
  if (p < 4)      { ta = 0; tb = p; }
  else if (p < 7) { ta = 1; tb = p - 3; }
  else if (p < 9) { ta = 2; tb = p - 5; }
  else            { ta = 3; tb = 3; }
}

// swizzled short-index into Xt[col][64 rows] (row-stride 64 shorts = 128 B).
// XOR bits 3..5 of row with g(col): b128 frag reads ~2-way, b64 writes 4-way.
__device__ __forceinline__ int swz(int col, int r) {
  int g = ((col >> 2) & 7) ^ ((col & 3) << 1);
  return col * 64 + (r ^ (g << 3));
}

// round-to-nearest-even fp32 -> bf16 (truncation would bias S by ~-2e3)
__device__ __forceinline__ unsigned short rne_bf16(float f) {
  unsigned u = __float_as_uint(f);
  return (unsigned short)((u + 0x7fffu + ((u >> 16) & 1u)) >> 16);
}

// ---------------------------------------------------------------------------
// Kernel 1: row inverse norms (one wave per row) + zero S/cnt.
// ---------------------------------------------------------------------------
__global__ __launch_bounds__(256) void k_prep(
    const float* __restrict__ x, float* __restrict__ inv,
    float* __restrict__ S, unsigned int* __restrict__ cnt, int N) {
  if (blockIdx.x == 0 && threadIdx.x == 0) { *S = 0.0f; *cnt = 0u; }
  int wave = (blockIdx.x * blockDim.x + threadIdx.x) >> 6;
  int lane = threadIdx.x & 63;
  if (wave >= N) return;
  const float4 v = reinterpret_cast<const float4*>(x + (size_t)wave * D)[lane];
  float s = v.x * v.x + v.y * v.y + v.z * v.z + v.w * v.w;
  #pragma unroll
  for (int o = 32; o > 0; o >>= 1) s += __shfl_xor(s, o);
  if (lane == 0) inv[wave] = 1.0f / fmaxf(sqrtf(s), EPS);
}

// ---------------------------------------------------------------------------
// Kernel 2: Gram tiles. grid (NPAIRS, N/CHUNK), 512 threads.
// Per block: 8 sub-chunks of 64 rows {reg-prefetch -> LDS transpose (bf16,
// swizzled) -> MFMA}, then ONE coalesced 16 KB slab store. No atomics.
// ---------------------------------------------------------------------------
__global__ __launch_bounds__(512) void k_gram(
    const float* __restrict__ x, const float* __restrict__ inv,
    float* __restrict__ slabs, int nchunk) {
  int ta, tb; pair_decode(blockIdx.x, ta, tb);
  const bool same = (ta == tb);
  const int row0 = blockIdx.y * CHUNK;

  __shared__ short X[128 * 64];     // [col][row], cols 0..63=A, 64..127=B
  const int tid = threadIdx.x;

  // staging task: 4 rows x 4 cols micro-transpose
  const int lcb = same ? 4 : 5;                 // log2(col-blocks)
  const int ntask = 16 << lcb;                  // 256 or 512
  const bool active = tid < ntask;
  const int c0 = (tid & ((1 << lcb) - 1)) << 2; // LDS col base
  const int r0 = (active ? (tid >> lcb) : 0) << 2;
  const int gc0 = (c0 < TILE) ? ta * TILE + c0 : tb * TILE + (c0 - TILE);

  // MFMA decomposition: wave w owns 16x32 of the 64x64 tile
  const int w = tid >> 6, lane = tid & 63;
  const int i0 = (w >> 1) << 4;                 // 0,16,32,48
  const int j0 = (w & 1) << 5;                  // 0,32
  const int lm = lane & 15, lk = lane >> 4;
  const int bbase = same ? 0 : 64;

  f32x4 zero = {0.f, 0.f, 0.f, 0.f};
  f32x4 acc[2] = {zero, zero};

  float4 pv[4]; float4 piv;
  if (active) {
    piv = *reinterpret_cast<const float4*>(&inv[row0 + r0]);
    const float* xb = x + (size_t)(row0 + r0) * D + gc0;
    #pragma unroll
    for (int jj = 0; jj < 4; ++jj)
      pv[jj] = *reinterpret_cast<const float4*>(xb + (size_t)jj * D);
  }

  const int NSUB = CHUNK / 64;                  // 8
  for (int s = 0; s < NSUB; ++s) {
    if (active) {
      const float ivv[4] = {piv.x, piv.y, piv.z, piv.w};
      unsigned short hh[4][4];
      #pragma unroll
      for (int jj = 0; jj < 4; ++jj) {
        const float vv[4] = {pv[jj].x, pv[jj].y, pv[jj].z, pv[jj].w};
        #pragma unroll
        for (int cc = 0; cc < 4; ++cc)
          hh[jj][cc] = rne_bf16(vv[cc] * ivv[jj]);
      }
      #pragma unroll
      for (int cc = 0; cc < 4; ++cc)
        *reinterpret_cast<ushort4*>(&X[swz(c0 + cc, r0)]) =
            make_ushort4(hh[0][cc], hh[1][cc], hh[2][cc], hh[3][cc]);
      if (s + 1 < NSUB) {                       // prefetch next sub-chunk
        const int nr0 = row0 + (s + 1) * 64 + r0;
        piv = *reinterpret_cast<const float4*>(&inv[nr0]);
        const float* xb = x + (size_t)nr0 * D + gc0;
        #pragma unroll
        for (int jj = 0; jj < 4; ++jj)
          pv[jj] = *reinterpret_cast<const float4*>(xb + (size_t)jj * D);
      }
    }
    __syncthreads();
    #pragma unroll
    for (int rr = 0; rr < 64; rr += 32) {
      const int rbase = rr + lk * 8;
      bf16x8 A  = *reinterpret_cast<const bf16x8*>(&X[swz(i0 + lm, rbase)]);
      bf16x8 B0 = *reinterpret_cast<const bf16x8*>(&X[swz(bbase + j0 + lm, rbase)]);
      bf16x8 B1 = *reinterpret_cast<const bf16x8*>(&X[swz(bbase + j0 + 16 + lm, rbase)]);
      acc[0] = __builtin_amdgcn_mfma_f32_16x16x32_bf16(A, B0, acc[0], 0, 0, 0);
      acc[1] = __builtin_amdgcn_mfma_f32_16x16x32_bf16(A, B1, acc[1], 0, 0, 0);
    }
    __syncthreads();
  }

  // slab store; C/D layout (m89): col = lane&15, row = (lane>>4)*4 + reg
  float* slab = slabs +
      ((size_t)blockIdx.x * nchunk + blockIdx.y) * (TILE * TILE);
  #pragma unroll
  for (int jt = 0; jt < 2; ++jt)
    #pragma unroll
    for (int rg = 0; rg < 4; ++rg)
      slab[(i0 + lk * 4 + rg) * TILE + (j0 + jt * 16 + lm)] = acc[jt][rg];
}

// ---------------------------------------------------------------------------
// Kernel 3: reduce. 160 blocks x 256 threads; one G element per thread:
// sum nchunk slab partials (coalesced), weight, square, block-reduce,
// atomicAdd(S) per block, last-block ticket writes the loss.
// ---------------------------------------------------------------------------
__global__ __launch_bounds__(256) void k_reduce(
    const float* __restrict__ slabs, float* __restrict__ S,
    unsigned int* __restrict__ cnt, float* __restrict__ out,
    int nchunk, int N, int nblocks) {
  const int g = blockIdx.x * 256 + threadIdx.x;
  const int p = g >> 12;                        // pair 0..9
  const int e = g & 4095;                       // element in 64x64 tile
  const float* base = slabs + (size_t)p * nchunk * (TILE * TILE) + e;
  float tot = 0.f;
  #pragma unroll 4
  for (int c = 0; c < nchunk; ++c) tot += base[(size_t)c * (TILE * TILE)];
  const bool diag = (p == 0) | (p == 4) | (p == 7) | (p == 9);
  float part = (diag ? 1.f : 2.f) * tot * tot;
  #pragma unroll
  for (int o = 32; o > 0; o >>= 1) part += __shfl_xor(part, o);
  __shared__ float red[4];
  int lane = threadIdx.x & 63, w = threadIdx.x >> 6;
  if (lane == 0) red[w] = part;
  __syncthreads();
  if (threadIdx.x == 0) {
    float blk = red[0] + red[1] + red[2] + red[3];
    atomicAdd(S, blk);
    __threadfence();
    unsigned int old = atomicAdd(cnt, 1u);
    if (old == (unsigned int)(nblocks - 1)) {
      float Sv = __hip_atomic_load(S, __ATOMIC_RELAXED,
                                   __HIP_MEMORY_SCOPE_AGENT);
      float nf = (float)N;
      out[0] = (Sv - nf) / (nf * nf - nf);
    }
  }
}

extern "C" void kernel_launch(void* const* d_in, const int* in_sizes, int n_in,
                              void* d_out, int out_size, void* d_ws, size_t ws_size,
                              hipStream_t stream) {
  const float* x = (const float*)d_in[0];
  float* out = (float*)d_out;
  const int N = in_sizes[0] / D;       // 8192
  const int nchunk = N / CHUNK;        // 16

  // ws layout (floats): inv[N] | S | cnt | pad to +64 | slabs[10*nchunk*4096]
  float* inv = (float*)d_ws;
  float* Sp = inv + N;
  unsigned int* cnt = (unsigned int*)(Sp + 1);
  float* slabs = inv + N + 64;

  k_prep<<<dim3(N / 4), dim3(256), 0, stream>>>(x, inv, Sp, cnt, N);
  k_gram<<<dim3(NPAIRS, nchunk), dim3(512), 0, stream>>>(x, inv, slabs, nchunk);
  const int nb = NPAIRS * (TILE * TILE / 256);  // 160
  k_reduce<<<dim3(nb), dim3(256), 0, stream>>>(slabs, Sp, cnt, out,
                                               nchunk, N, nb);
}